// Round 3
// baseline (317.738 us; speedup 1.0000x reference)
//
#include <hip/hip_runtime.h>
#include <hip/hip_bf16.h>

typedef __bf16 bf16x8 __attribute__((ext_vector_type(8)));
typedef __bf16 bf16x4 __attribute__((ext_vector_type(4)));
typedef float  f32x4  __attribute__((ext_vector_type(4)));

#define K_DIM 1024
#define N_DIM 1024
#define BM 128
#define BN 128
#define BK 64

typedef unsigned int u32;
typedef u32 __attribute__((address_space(1))) u32_g;
typedef u32 __attribute__((address_space(3))) u32_s;

__device__ __forceinline__ void load16_lds(const void* g, void* s) {
    // async global->LDS, 16B per lane; LDS dest = wave-uniform base + lane*16
    __builtin_amdgcn_global_load_lds((u32_g*)g, (u32_s*)s, 16, 0, 0);
}

// ---------------- 1. per-block max|kernel| (no atomics, no memset) ----------------
__global__ void maxabs_kernel(const float* __restrict__ w, float* __restrict__ blockmax, int n4) {
    __shared__ float sm[4];
    int i = blockIdx.x * blockDim.x + threadIdx.x;
    int stride = gridDim.x * blockDim.x;
    float m = 0.f;
    for (; i < n4; i += stride) {
        float4 v = ((const float4*)w)[i];
        m = fmaxf(m, fmaxf(fmaxf(fabsf(v.x), fabsf(v.y)), fmaxf(fabsf(v.z), fabsf(v.w))));
    }
#pragma unroll
    for (int off = 32; off > 0; off >>= 1)
        m = fmaxf(m, __shfl_down(m, off, 64));
    int lane = threadIdx.x & 63, wave = threadIdx.x >> 6;
    if (lane == 0) sm[wave] = m;
    __syncthreads();
    if (threadIdx.x == 0)
        blockmax[blockIdx.x] = fmaxf(fmaxf(sm[0], sm[1]), fmaxf(sm[2], sm[3]));
}

// ---------------- 2. W_eff^T (N x K, bf16) = quant-dequant(kernel) + a@b ----------------
__global__ void build_w_kernel(const float* __restrict__ kern, const float* __restrict__ amat,
                               const float* __restrict__ bmat, const float* __restrict__ blockmax,
                               __bf16* __restrict__ wt) {
    __shared__ float smax;
    if (threadIdx.x < 64) {
        float m = 0.f;
#pragma unroll
        for (int j = 0; j < 4; ++j) m = fmaxf(m, blockmax[threadIdx.x + j * 64]);
#pragma unroll
        for (int off = 32; off > 0; off >>= 1)
            m = fmaxf(m, __shfl_down(m, off, 64));
        if (threadIdx.x == 0) smax = m;
    }
    __syncthreads();
    float scale = smax * (1.0f / 7.0f);

    int t = blockIdx.x * blockDim.x + threadIdx.x;   // 0 .. 1M-1
    int k = t & (K_DIM - 1);
    int n = t >> 10;
    float w = kern[k * N_DIM + n];
    float q = rintf(w / scale);                      // RNE == jnp.round
    q = fminf(fmaxf(q, -8.f), 7.f);
    float acc = q * scale;
#pragma unroll
    for (int r = 0; r < 16; ++r)
        acc += amat[k * 16 + r] * bmat[r * N_DIM + n];
    wt[(size_t)n * K_DIM + k] = (__bf16)acc;
}

// ---------------- 3. GEMM: out[M,N] = x[M,K](fp32) * Wt[N,K]^T + bias ----------------
// x is read fp32 directly; conversion to bf16 happens during LDS staging
// (eliminates the standalone cvt pass and its 192 MiB of traffic).
// B tile stays on the async global_load_lds path (DMA overlaps A's cvt work).
// XCD-aware swizzle: all 8 N-tiles of one M-panel land on the SAME XCD, so the
// x panel is fetched into that XCD's L2 once and reused 8x.
// LDS layout (As and Bs): row-major [row][64 bf16], 16B chunk c of row r stored
// at physical chunk c ^ (r&7) -> conflict-free ds_read_b128.
__global__ __launch_bounds__(256, 3)
void gemm_kernel(const float* __restrict__ x, const __bf16* __restrict__ wt,
                 const float* __restrict__ bias, float* __restrict__ out) {
    __shared__ __attribute__((aligned(16))) __bf16 As[BM * BK];
    __shared__ __attribute__((aligned(16))) __bf16 Bs[BN * BK];

    const int tid  = threadIdx.x;
    const int lane = tid & 63;
    const int wave = tid >> 6;
    const int wm = (wave >> 1) * 64;
    const int wn = (wave & 1) * 64;

    // swizzle: l%8 = xcd; i=l/8; n_tile = i%8; m_panel = (i/8)*8 + l%8
    const int l = blockIdx.x;
    const int i = l >> 3;
    const int bn0 = (i & 7) * BN;
    const int bm0 = (((i >> 3) << 3) | (l & 7)) * BM;

    const int l15 = lane & 15;
    const int l4  = lane >> 4;

    f32x4 acc[4][4] = {};

    // B staging geometry: 64 lanes x 16B = 8 rows (128B each) per wave-issue
    const int srow = lane >> 3;           // row within the 8-row group
    const int gch  = (lane & 7) ^ srow;   // swizzled source chunk

    // A staging geometry (fp32->bf16): thread covers float4 f = j*256+tid
    const int ar0 = tid >> 4;             // row for j=0 (rows advance by 16/j)
    const int ac4 = tid & 15;             // 4-float column group

    for (int k0 = 0; k0 < K_DIM; k0 += BK) {
        __syncthreads();
        // ---- stage B tile (Wt rows = n), async DMA ----
#pragma unroll
        for (int j = 0; j < 4; ++j) {
            int r = j * 32 + wave * 8;    // wave-uniform base row
            const __bf16* g = wt + (size_t)(bn0 + r + srow) * K_DIM + k0 + gch * 8;
            load16_lds(g, &Bs[r * BK]);
        }
        // ---- stage A tile: fp32 load + cvt + LDS write (overlaps B's DMA) ----
#pragma unroll
        for (int j = 0; j < 8; ++j) {
            int r = ar0 + j * 16;
            float4 v = *(const float4*)(x + (size_t)(bm0 + r) * K_DIM + k0 + ac4 * 4);
            int p = (ac4 >> 1) ^ (r & 7);
            bf16x4 o;
            o.x = (__bf16)v.x; o.y = (__bf16)v.y; o.z = (__bf16)v.z; o.w = (__bf16)v.w;
            *(bf16x4*)(&As[r * BK + p * 8 + (ac4 & 1) * 4]) = o;
        }
        __syncthreads();

        // ---- compute: 2 k-steps x 16 MFMA(16x16x32) per wave ----
#pragma unroll
        for (int ks = 0; ks < 2; ++ks) {
            bf16x8 af[4], bfr[4];
#pragma unroll
            for (int mt = 0; mt < 4; ++mt) {
                int r = wm + mt * 16 + l15;
                int p = (ks * 4 + l4) ^ (r & 7);
                af[mt] = *(const bf16x8*)(&As[r * BK + p * 8]);
            }
#pragma unroll
            for (int nt = 0; nt < 4; ++nt) {
                int r = wn + nt * 16 + l15;
                int p = (ks * 4 + l4) ^ (r & 7);
                bfr[nt] = *(const bf16x8*)(&Bs[r * BK + p * 8]);
            }
#pragma unroll
            for (int mt = 0; mt < 4; ++mt)
#pragma unroll
                for (int nt = 0; nt < 4; ++nt)
                    acc[mt][nt] = __builtin_amdgcn_mfma_f32_16x16x32_bf16(
                        af[mt], bfr[nt], acc[mt][nt], 0, 0, 0);
        }
    }

    // ---- epilogue: C/D layout col = lane&15, row = (lane>>4)*4 + reg ----
#pragma unroll
    for (int nt = 0; nt < 4; ++nt) {
        int n = bn0 + wn + nt * 16 + l15;
        float bv = bias[n];
#pragma unroll
        for (int mt = 0; mt < 4; ++mt) {
            int m = bm0 + wm + mt * 16 + l4 * 4;
            float* op = out + (size_t)m * N_DIM + n;
#pragma unroll
            for (int r = 0; r < 4; ++r)
                op[(size_t)r * N_DIM] = acc[mt][nt][r] + bv;
        }
    }
}

extern "C" void kernel_launch(void* const* d_in, const int* in_sizes, int n_in,
                              void* d_out, int out_size, void* d_ws, size_t ws_size,
                              hipStream_t stream) {
    const float* x    = (const float*)d_in[0];
    const float* kern = (const float*)d_in[1];
    const float* bias = (const float*)d_in[2];
    const float* amat = (const float*)d_in[3];
    const float* bmat = (const float*)d_in[4];
    float* out = (float*)d_out;
    const int M = in_sizes[0] / K_DIM;   // 32768

    float* blockmax = (float*)d_ws;                          // 256 floats
    __bf16* wt = (__bf16*)((char*)d_ws + 4096);              // 2 MiB

    maxabs_kernel<<<256, 256, 0, stream>>>(kern, blockmax, K_DIM * N_DIM / 4);
    build_w_kernel<<<K_DIM * N_DIM / 256, 256, 0, stream>>>(kern, amat, bmat, blockmax, wt);

    const int nblocks = (M / BM) * (N_DIM / BN);
    gemm_kernel<<<nblocks, 256, 0, stream>>>(x, wt, bias, out);
}